// Round 2
// baseline (1114.218 us; speedup 1.0000x reference)
//
#include <hip/hip_runtime.h>
#include <cstdint>
#include <type_traits>

typedef short bf16x8 __attribute__((ext_vector_type(8)));
typedef float f32x4 __attribute__((ext_vector_type(4)));

__device__ __forceinline__ ushort f2bf(float f) {
  union { float f; uint32_t u; } v; v.f = f;
  return (ushort)((v.u + 0x7fffu + ((v.u >> 16) & 1u)) >> 16);
}
__device__ __forceinline__ float bf2f(ushort u) {
  union { uint32_t u; float f; } v; v.u = ((uint32_t)u) << 16;
  return v.f;
}
// pack two fp32 -> two bf16 (round-half-up; ties-only deviation from RNE)
__device__ __forceinline__ uint32_t pkbf(float x, float y) {
  uint32_t ux = (__float_as_uint(x) + 0x8000u) >> 16;
  uint32_t uy = (__float_as_uint(y) + 0x8000u) & 0xffff0000u;
  return ux | uy;
}

// load 8 K-contiguous elements as 8 bf16 packed in a uint4
__device__ __forceinline__ uint4 ld8(const ushort* p) { return *(const uint4*)p; }
__device__ __forceinline__ uint4 ld8(const float* p) {
  float4 a = *(const float4*)p;
  float4 b = *(const float4*)(p + 4);
  uint4 r;
  r.x = pkbf(a.x, a.y); r.y = pkbf(a.z, a.w);
  r.z = pkbf(b.x, b.y); r.w = pkbf(b.z, b.w);
  return r;
}

// ---------------------------------------------------------------------------
// GEMM: C[M,N] = A[M,K] * B[N,K]^T.  TA/TB in {float fp32, ushort bf16-bits};
// TC in {ushort bf16, float}.  128x128 tile, BK=32, 4 waves 2x2, 4x4 MFMA each.
// TRANSC: C[col*ldc + row] (builds Vt[n][s]).
// ---------------------------------------------------------------------------
template <bool TRANSC, typename TA, typename TB, typename TC>
__global__ __launch_bounds__(256) void gemm_bt(
    const TA* __restrict__ A, const TB* __restrict__ B,
    TC* __restrict__ C, int M, int N, int K, int ldc)
{
  __shared__ __align__(16) ushort As[128 * 32];
  __shared__ __align__(16) ushort Bs[128 * 32];

  const int tid  = threadIdx.x;
  const int wave = tid >> 6;
  const int lane = tid & 63;
  const int quad = lane >> 4;
  const int l16  = lane & 15;
  const int m0 = blockIdx.y * 128;
  const int n0 = blockIdx.x * 128;
  const int wm = (wave & 1) * 64;
  const int wn = (wave >> 1) * 64;
  const int r0 = tid >> 2;          // 0..63 staging row
  const int c0 = (tid & 3) * 8;     // staging col (8 elements)

  f32x4 acc[4][4];
#pragma unroll
  for (int i = 0; i < 4; i++)
#pragma unroll
    for (int j = 0; j < 4; j++) acc[i][j] = {0.f, 0.f, 0.f, 0.f};

  const TA* aptr = A + (size_t)(m0 + r0) * K + c0;
  const TB* bptr = B + (size_t)(n0 + r0) * K + c0;

  for (int k0 = 0; k0 < K; k0 += 32) {
    uint4 av0 = ld8(aptr + k0);
    uint4 av1 = ld8(aptr + (size_t)64 * K + k0);
    uint4 bv0 = ld8(bptr + k0);
    uint4 bv1 = ld8(bptr + (size_t)64 * K + k0);
    __syncthreads();
    *(uint4*)(As + r0 * 32 + c0)        = av0;
    *(uint4*)(As + (r0 + 64) * 32 + c0) = av1;
    *(uint4*)(Bs + r0 * 32 + c0)        = bv0;
    *(uint4*)(Bs + (r0 + 64) * 32 + c0) = bv1;
    __syncthreads();

    bf16x8 af[4], bfr[4];
#pragma unroll
    for (int i = 0; i < 4; i++) {
      af[i]  = *(const bf16x8*)(As + (wm + i * 16 + l16) * 32 + quad * 8);
      bfr[i] = *(const bf16x8*)(Bs + (wn + i * 16 + l16) * 32 + quad * 8);
    }
#pragma unroll
    for (int im = 0; im < 4; im++)
#pragma unroll
      for (int in = 0; in < 4; in++)
        acc[im][in] = __builtin_amdgcn_mfma_f32_16x16x32_bf16(
            af[im], bfr[in], acc[im][in], 0, 0, 0);
  }

  // C/D layout: col = lane&15, row = quad*4 + reg
#pragma unroll
  for (int im = 0; im < 4; im++)
#pragma unroll
    for (int in = 0; in < 4; in++)
#pragma unroll
      for (int r = 0; r < 4; r++) {
        int row = m0 + wm + im * 16 + quad * 4 + r;
        int col = n0 + wn + in * 16 + l16;
        float fv = acc[im][in][r];
        TC val;
        if constexpr (std::is_same<TC, ushort>::value) val = f2bf(fv);
        else                                           val = fv;
        if (TRANSC) C[(size_t)col * ldc + row] = val;
        else        C[(size_t)row * ldc + col] = val;
      }
}

// ---------------------------------------------------------------------------
// RoPE on K (bf16 ws) in place: K[s, h*128+j], pairs (j, j+64),
// angle = s * 10000^(-j/64)
// ---------------------------------------------------------------------------
__global__ __launch_bounds__(256) void rope_kernel(ushort* __restrict__ Kb)
{
  int idx = blockIdx.x * 256 + threadIdx.x;   // 2048*32*64 threads
  int j  = idx & 63;
  int hs = idx >> 6;                          // s*32 + h
  int s  = hs >> 5;
  float freq = expf(-0.14391156f * (float)j); // 10000^(-j/64)
  float ang  = (float)s * freq;
  float sn, c;
  sincosf(ang, &sn, &c);
  size_t base = (size_t)hs * 128 + j;         // = s*4096 + h*128 + j
  float k1 = bf2f(Kb[base]);
  float k2 = bf2f(Kb[base + 64]);
  Kb[base]      = f2bf(k1 * c - k2 * sn);
  Kb[base + 64] = f2bf(k2 * c + k1 * sn);
}

// ---------------------------------------------------------------------------
// Flash attention. Block = 1 head x 64 q-rows (4 waves x 16 rows).
// Q: [2048,4096] bf16. K: same (roped). Vt: [4096,2048] bf16 (Vt[n][s]).
// KV tiles of 128 staged in LDS with XOR-of-16B-group swizzle.
// ---------------------------------------------------------------------------
__global__ __launch_bounds__(256) void flash_attn(
    const ushort* __restrict__ Q, const ushort* __restrict__ Kb,
    const ushort* __restrict__ Vt, ushort* __restrict__ AO)
{
  __shared__ __align__(16) ushort Kt[128 * 128];     // [kn][d] swizzled
  __shared__ __align__(16) ushort Vs[128 * 128];     // [d][kn] swizzled
  __shared__ __align__(16) ushort Ps[4][16 * 128];   // per-wave P [qrow][kn] swizzled

  const int tid  = threadIdx.x;
  const int wave = tid >> 6;
  const int lane = tid & 63;
  const int quad = lane >> 4;
  const int l16  = lane & 15;
  const int h  = blockIdx.y;
  const int q0 = blockIdx.x * 64 + wave * 16;
  const float scale = 0.08838834764831845f;  // 1/sqrt(128)

  // Q A-operand frags: A[m=lane&15][k=quad*8+j]
  bf16x8 aq[4];
#pragma unroll
  for (int kt = 0; kt < 4; kt++)
    aq[kt] = *(const bf16x8*)(Q + (size_t)(q0 + l16) * 4096 + h * 128 + kt * 32 + quad * 8);

  f32x4 Oacc[8];
#pragma unroll
  for (int dt = 0; dt < 8; dt++) Oacc[dt] = {0.f, 0.f, 0.f, 0.f};
  float m_i[4], l_i[4];
#pragma unroll
  for (int r = 0; r < 4; r++) { m_i[r] = -1e30f; l_i[r] = 0.f; }

  ushort* myP = &Ps[wave][0];

  for (int kv = 0; kv < 2048; kv += 128) {
    __syncthreads();
#pragma unroll
    for (int it = 0; it < 8; it++) {
      int i   = tid + it * 256;     // 0..2047
      int row = i >> 4;             // 0..127 (kn for K, d for V)
      int g   = i & 15;             // 16B group
      int sw  = (g ^ (row & 15)) * 8;
      *(uint4*)(Kt + row * 128 + sw) =
          *(const uint4*)(Kb + (size_t)(kv + row) * 4096 + h * 128 + g * 8);
      *(uint4*)(Vs + row * 128 + sw) =
          *(const uint4*)(Vt + (size_t)(h * 128 + row) * 2048 + kv + g * 8);
    }
    __syncthreads();

    // S = Q K^T (raw; scale applied in softmax)
    f32x4 sA[8];
#pragma unroll
    for (int nt = 0; nt < 8; nt++) sA[nt] = {0.f, 0.f, 0.f, 0.f};
#pragma unroll
    for (int nt = 0; nt < 8; nt++) {
      int row = nt * 16 + l16;
#pragma unroll
      for (int kt = 0; kt < 4; kt++) {
        int g = kt * 4 + quad;
        bf16x8 bk = *(const bf16x8*)(Kt + row * 128 + ((g ^ (row & 15)) * 8));
        sA[nt] = __builtin_amdgcn_mfma_f32_16x16x32_bf16(aq[kt], bk, sA[nt], 0, 0, 0);
      }
    }

    // online softmax; lane holds rows quad*4+r, cols nt*16+l16
    float tmax[4];
#pragma unroll
    for (int r = 0; r < 4; r++) {
      float m = sA[0][r];
#pragma unroll
      for (int nt = 1; nt < 8; nt++) m = fmaxf(m, sA[nt][r]);
      tmax[r] = m;
    }
#pragma unroll
    for (int msk = 1; msk < 16; msk <<= 1)
#pragma unroll
      for (int r = 0; r < 4; r++)
        tmax[r] = fmaxf(tmax[r], __shfl_xor(tmax[r], msk));

    float alpha[4];
#pragma unroll
    for (int r = 0; r < 4; r++) {
      float mn = fmaxf(m_i[r], tmax[r] * scale);
      alpha[r] = __expf(m_i[r] - mn);
      m_i[r] = mn;
    }
    float rsum[4] = {0.f, 0.f, 0.f, 0.f};
#pragma unroll
    for (int nt = 0; nt < 8; nt++)
#pragma unroll
      for (int r = 0; r < 4; r++) {
        float p = __expf(sA[nt][r] * scale - m_i[r]);
        sA[nt][r] = p;
        rsum[r] += p;
      }
#pragma unroll
    for (int msk = 1; msk < 16; msk <<= 1)
#pragma unroll
      for (int r = 0; r < 4; r++) rsum[r] += __shfl_xor(rsum[r], msk);
#pragma unroll
    for (int r = 0; r < 4; r++) l_i[r] = l_i[r] * alpha[r] + rsum[r];

    // P (C-layout) -> LDS bf16 [qrow][kn] swizzled
#pragma unroll
    for (int nt = 0; nt < 8; nt++)
#pragma unroll
      for (int r = 0; r < 4; r++) {
        int row = quad * 4 + r;
        int col = nt * 16 + l16;
        myP[row * 128 + (((col >> 3) ^ row) * 8) + (col & 7)] = f2bf(sA[nt][r]);
      }

    // rescale O
#pragma unroll
    for (int dt = 0; dt < 8; dt++)
#pragma unroll
      for (int r = 0; r < 4; r++) Oacc[dt][r] *= alpha[r];

    // O += P V : A = P[qrow][kn], B[n=d][k=kn] = Vs[d][kn]
#pragma unroll
    for (int kt = 0; kt < 4; kt++) {
      int g = kt * 4 + quad;
      bf16x8 ap = *(const bf16x8*)(myP + l16 * 128 + ((g ^ l16) * 8));
#pragma unroll
      for (int dt = 0; dt < 8; dt++) {
        int vrow = dt * 16 + l16;
        bf16x8 bv = *(const bf16x8*)(Vs + vrow * 128 + ((g ^ (vrow & 15)) * 8));
        Oacc[dt] = __builtin_amdgcn_mfma_f32_16x16x32_bf16(ap, bv, Oacc[dt], 0, 0, 0);
      }
    }
  }

  // epilogue: O / l
#pragma unroll
  for (int dt = 0; dt < 8; dt++)
#pragma unroll
    for (int r = 0; r < 4; r++) {
      int row = q0 + quad * 4 + r;
      int col = h * 128 + dt * 16 + l16;
      AO[(size_t)row * 4096 + col] = f2bf(Oacc[dt][r] / l_i[r]);
    }
}

// ---------------------------------------------------------------------------
extern "C" void kernel_launch(void* const* d_in, const int* in_sizes, int n_in,
                              void* d_out, int out_size, void* d_ws, size_t ws_size,
                              hipStream_t stream)
{
  const float* hidden  = (const float*)d_in[0];
  // d_in[1] = attention_mask (all ones) -- unused
  const float* Wq      = (const float*)d_in[2];
  const float* Wk      = (const float*)d_in[3];
  const float* Wv      = (const float*)d_in[4];
  const float* Wo      = (const float*)d_in[5];
  const float* latents = (const float*)d_in[6];
  float* out = (float*)d_out;

  const size_t MB16 = (size_t)2048 * 4096;  // elements per [2048,4096] bf16 buffer
  char* w = (char*)d_ws;
  ushort* Qb  = (ushort*)w;
  ushort* Kbf = (ushort*)(w + MB16 * 2);
  ushort* Vtb = (ushort*)(w + MB16 * 4);
  ushort* AOb = (ushort*)(w + MB16 * 6);

  dim3 gemm_grid(32, 16);  // N/128, M/128

  // Q = latents @ Wq^T   (fp32 in -> bf16 ws)
  gemm_bt<false><<<gemm_grid, 256, 0, stream>>>(latents, Wq, Qb, 2048, 4096, 4096, 4096);
  // K = hidden @ Wk^T
  gemm_bt<false><<<gemm_grid, 256, 0, stream>>>(hidden, Wk, Kbf, 2048, 4096, 4096, 4096);
  // Vt = (hidden @ Wv^T)^T -> Vt[n][s], ldc = 2048
  gemm_bt<true><<<gemm_grid, 256, 0, stream>>>(hidden, Wv, Vtb, 2048, 4096, 4096, 2048);
  // RoPE on K in place
  rope_kernel<<<(2048 * 32 * 64) / 256, 256, 0, stream>>>(Kbf);
  // attention (bf16 ws -> bf16 ws)
  flash_attn<<<dim3(32, 32), 256, 0, stream>>>(Qb, Kbf, Vtb, AOb);
  // out = AO @ Wo^T  (bf16 ws x fp32 -> fp32 out)
  gemm_bt<false><<<gemm_grid, 256, 0, stream>>>(AOb, Wo, out, 2048, 4096, 4096, 4096);
}